// Round 5
// baseline (211.170 us; speedup 1.0000x reference)
//
#include <hip/hip_runtime.h>
#include <hip/hip_bf16.h>

#define NTOK 2048
#define CDIM 256
#define QKVD 768   // 3*C
#define HEADS 8
#define HD 32
#define SCALE 0.17677669529663687f  // 1/sqrt(32)

typedef __attribute__((ext_vector_type(8))) short short8;
typedef __attribute__((ext_vector_type(4))) float float4v;
typedef unsigned short ushort_t;
typedef unsigned int uint_t;

#define MFMA(a, b, c) __builtin_amdgcn_mfma_f32_16x16x32_bf16(a, b, c, 0, 0, 0)

__device__ __forceinline__ uint_t f2bf(float f) {
    uint_t u = __float_as_uint(f);
    return (u + 0x7fffu + ((u >> 16) & 1u)) >> 16;   // RTNE
}
__device__ __forceinline__ uint_t pack2(float a, float b) {
    return f2bf(a) | (f2bf(b) << 16);
}

// ---------------- K1: qkv GEMM, f32 compute, bf16 layout-aware epilogue ----------------
// qkv[d][n] = sum_c x[b][n][c] * w[d][c];  d = h*96 + t
//   t in [0,32):  q_t[bh][n][t]     (d-fast, scale folded)
//   t in [32,64): k_t[bh][n][t-32]  (d-fast)
//   t in [64,96): v [bh][t-64][n]   (n-fast)
// grid (768/64, 2048/64, B), block 256
__global__ __launch_bounds__(256) void qkv_gemm(const float* __restrict__ x,
                                                const float* __restrict__ w,
                                                ushort_t* __restrict__ q_t,
                                                ushort_t* __restrict__ k_t,
                                                ushort_t* __restrict__ v_) {
    __shared__ float a_lds[64][17];
    __shared__ float b_lds[64][17];
    const int b = blockIdx.z;
    const int dtile = blockIdx.x * 64;
    const int ntile = blockIdx.y * 64;
    const int tid = threadIdx.x;
    const int tx = tid & 15, ty = tid >> 4;
    const int lrow = tid >> 2;        // 0..63
    const int lcq  = (tid & 3) * 4;   // 0,4,8,12

    float acc[4][4] = {};

    for (int k0 = 0; k0 < CDIM; k0 += 16) {
        float4 av = *(const float4*)&w[(size_t)(dtile + lrow) * CDIM + k0 + lcq];
        float4 bv = *(const float4*)&x[((size_t)b * NTOK + ntile + lrow) * CDIM + k0 + lcq];
        a_lds[lrow][lcq+0] = av.x; a_lds[lrow][lcq+1] = av.y;
        a_lds[lrow][lcq+2] = av.z; a_lds[lrow][lcq+3] = av.w;
        b_lds[lrow][lcq+0] = bv.x; b_lds[lrow][lcq+1] = bv.y;
        b_lds[lrow][lcq+2] = bv.z; b_lds[lrow][lcq+3] = bv.w;
        __syncthreads();
        #pragma unroll
        for (int kk = 0; kk < 16; ++kk) {
            float ar[4], br[4];
            #pragma unroll
            for (int i = 0; i < 4; ++i) ar[i] = a_lds[ty*4+i][kk];
            #pragma unroll
            for (int j = 0; j < 4; ++j) br[j] = b_lds[tx*4+j][kk];
            #pragma unroll
            for (int i = 0; i < 4; ++i)
                #pragma unroll
                for (int j = 0; j < 4; ++j)
                    acc[i][j] += ar[i] * br[j];
        }
        __syncthreads();
    }

    #pragma unroll
    for (int i = 0; i < 4; ++i) {
        const int d = dtile + ty*4 + i;
        const int h = (d * 683) >> 16;       // d / 96 for d < 768
        const int t = d - h * 96;
        const size_t bh = (size_t)(b * HEADS + h);
        #pragma unroll
        for (int j = 0; j < 4; ++j) {
            const int n = ntile + tx*4 + j;
            const float val = acc[i][j];
            if (t < 64) {
                const int sel = t >> 5, dm = t & 31;
                ushort_t* dst = (sel ? k_t : q_t) + bh * (NTOK * HD) + (size_t)n * HD + dm;
                *dst = (ushort_t)f2bf(sel ? val : val * SCALE);
            } else {
                v_[bh * (NTOK * HD) + (size_t)(t - 64) * NTOK + n] = (ushort_t)f2bf(val);
            }
        }
    }
}

// ---------------- K2: MFMA flash attention (no-max softmax, barrier-free) ----------------
// Per wave: 32 queries. Per 32-key tile: S = K_t x Q (4 mfma 16x16x32, K=d=32),
// P = exp(S), P -> LDS (transposed [j][i], 80B row), PV (4 mfma, K=i=32).
// grid (2048/128, B*H), block 256 (4 independent waves)
__global__ __launch_bounds__(256) void attn_mfma(const ushort_t* __restrict__ q_t,
                                                 const ushort_t* __restrict__ k_t,
                                                 const ushort_t* __restrict__ v_,
                                                 float* __restrict__ pre) {
    __shared__ uint_t pt[4][2][16 * 20];   // [wave][qs][16 rows x 80B]
    const int tid = threadIdx.x, wave = tid >> 6, lane = tid & 63;
    const int l15 = lane & 15, g = lane >> 4;
    const int bh = blockIdx.y, b = bh >> 3, h = bh & 7;
    const int j0 = blockIdx.x * 128 + wave * 32;

    const ushort_t* qb = q_t + (size_t)bh * (NTOK * HD);
    const ushort_t* kb = k_t + (size_t)bh * (NTOK * HD);
    const ushort_t* vb = v_  + (size_t)bh * (NTOK * HD);

    // Q fragments (B operand): lane holds q_t[j0+qs*16+l15][g*8 .. g*8+7]
    short8 qf0 = *(const short8*)&qb[(size_t)(j0 + l15) * HD + g * 8];
    short8 qf1 = *(const short8*)&qb[(size_t)(j0 + 16 + l15) * HD + g * 8];

    const float4v z4 = {0.f, 0.f, 0.f, 0.f};
    float4v o00 = z4, o01 = z4, o10 = z4, o11 = z4;   // o[dsub][qs]
    float lsum0 = 0.f, lsum1 = 0.f;

    uint_t* pt0 = &pt[wave][0][0];
    uint_t* pt1 = &pt[wave][1][0];
    const int wbase = l15 * 20 + g * 2;   // u32 index for P writes
    const int rbase = l15 * 20 + g * 4;   // u32 index for P b128 reads

    for (int i0 = 0; i0 < NTOK; i0 += 32) {
        // K fragments (A operand): lane holds k_t[i0+ks*16+l15][g*8 .. g*8+7]
        short8 aK0 = *(const short8*)&kb[(size_t)(i0 + l15) * HD + g * 8];
        short8 aK1 = *(const short8*)&kb[(size_t)(i0 + 16 + l15) * HD + g * 8];

        float4v s00 = MFMA(aK0, qf0, z4);  // [ks=0][qs=0]
        float4v s10 = MFMA(aK1, qf0, z4);
        float4v s01 = MFMA(aK0, qf1, z4);
        float4v s11 = MFMA(aK1, qf1, z4);

        // exp + accumulate partial sums + pack bf16 + write P_t
        {
            float e0[4], e1[4];
            #pragma unroll
            for (int r = 0; r < 4; ++r) { e0[r] = __expf(s00[r]); e1[r] = __expf(s10[r]); }
            lsum0 += e0[0]+e0[1]+e0[2]+e0[3] + e1[0]+e1[1]+e1[2]+e1[3];
            pt0[wbase]     = pack2(e0[0], e0[1]);
            pt0[wbase + 1] = pack2(e0[2], e0[3]);
            pt0[wbase + 8] = pack2(e1[0], e1[1]);   // ks=1 -> +32B
            pt0[wbase + 9] = pack2(e1[2], e1[3]);
        }
        {
            float e0[4], e1[4];
            #pragma unroll
            for (int r = 0; r < 4; ++r) { e0[r] = __expf(s01[r]); e1[r] = __expf(s11[r]); }
            lsum1 += e0[0]+e0[1]+e0[2]+e0[3] + e1[0]+e1[1]+e1[2]+e1[3];
            pt1[wbase]     = pack2(e0[0], e0[1]);
            pt1[wbase + 1] = pack2(e0[2], e0[3]);
            pt1[wbase + 8] = pack2(e1[0], e1[1]);
            pt1[wbase + 9] = pack2(e1[2], e1[3]);
        }

        // P as B operand: lane reads P_t[l15][g*8 .. g*8+7] (16B)
        short8 pB0 = *(const short8*)&pt0[rbase];
        short8 pB1 = *(const short8*)&pt1[rbase];

        // V fragments (A operand): lane holds v[dsub*16+l15][i0+g*8 .. +7]
        short8 aV0 = *(const short8*)&vb[(size_t)l15 * NTOK + i0 + g * 8];
        short8 aV1 = *(const short8*)&vb[(size_t)(16 + l15) * NTOK + i0 + g * 8];

        o00 = MFMA(aV0, pB0, o00);
        o01 = MFMA(aV0, pB1, o01);
        o10 = MFMA(aV1, pB0, o10);
        o11 = MFMA(aV1, pB1, o11);
    }

    // finish softmax denominators: reduce across the 4 lane-groups
    lsum0 += __shfl_xor(lsum0, 16, 64); lsum0 += __shfl_xor(lsum0, 32, 64);
    lsum1 += __shfl_xor(lsum1, 16, 64); lsum1 += __shfl_xor(lsum1, 32, 64);
    const float rl0 = 1.f / lsum0, rl1 = 1.f / lsum1;

    float* pb_ = pre + ((size_t)b * CDIM + h * HD) * NTOK + j0;
    #pragma unroll
    for (int r = 0; r < 4; ++r) {
        const size_t row0 = (size_t)(g * 4 + r) * NTOK;
        const size_t row1 = (size_t)(16 + g * 4 + r) * NTOK;
        pb_[row0 + l15]      = o00[r] * rl0;
        pb_[row0 + 16 + l15] = o01[r] * rl1;
        pb_[row1 + l15]      = o10[r] * rl0;
        pb_[row1 + 16 + l15] = o11[r] * rl1;
    }
}

// ---------------- K3: out[b][dd][n] = sum_c w2[dd][c]*pre[b][c][n] + pb[dd] ----------------
// grid (256/64, 2048/64, B), block 256
__global__ __launch_bounds__(256) void proj_gemm(const float* __restrict__ pre,
                                                 const float* __restrict__ w2,
                                                 const float* __restrict__ pb,
                                                 float* __restrict__ out) {
    __shared__ float a_lds[64][17];
    __shared__ float b_lds[16][65];
    const int b = blockIdx.z;
    const int dtile = blockIdx.x * 64;
    const int ntile = blockIdx.y * 64;
    const int tid = threadIdx.x;
    const int tx = tid & 15, ty = tid >> 4;
    const int lrow = tid >> 2;
    const int lcq  = (tid & 3) * 4;

    float acc[4][4] = {};

    for (int k0 = 0; k0 < CDIM; k0 += 16) {
        float4 av = *(const float4*)&w2[(size_t)(dtile + lrow) * CDIM + k0 + lcq];
        a_lds[lrow][lcq+0] = av.x; a_lds[lrow][lcq+1] = av.y;
        a_lds[lrow][lcq+2] = av.z; a_lds[lrow][lcq+3] = av.w;
        #pragma unroll
        for (int it = 0; it < 4; ++it) {
            int krow = (tid >> 6) + it * 4;   // 0..15
            int col = tid & 63;
            b_lds[krow][col] = pre[((size_t)b * CDIM + k0 + krow) * NTOK + ntile + col];
        }
        __syncthreads();
        #pragma unroll
        for (int kk = 0; kk < 16; ++kk) {
            float ar[4], br[4];
            #pragma unroll
            for (int i = 0; i < 4; ++i) ar[i] = a_lds[ty*4+i][kk];
            #pragma unroll
            for (int j = 0; j < 4; ++j) br[j] = b_lds[kk][tx*4+j];
            #pragma unroll
            for (int i = 0; i < 4; ++i)
                #pragma unroll
                for (int j = 0; j < 4; ++j)
                    acc[i][j] += ar[i] * br[j];
        }
        __syncthreads();
    }
    #pragma unroll
    for (int i = 0; i < 4; ++i) {
        const int d = dtile + ty*4 + i;
        const float bias = pb[d];
        float4 st = make_float4(acc[i][0] + bias, acc[i][1] + bias,
                                acc[i][2] + bias, acc[i][3] + bias);
        *(float4*)&out[((size_t)b * CDIM + d) * NTOK + ntile + tx*4] = st;
    }
}

extern "C" void kernel_launch(void* const* d_in, const int* in_sizes, int n_in,
                              void* d_out, int out_size, void* d_ws, size_t ws_size,
                              hipStream_t stream) {
    const float* x      = (const float*)d_in[0];   // [4,2048,256]
    const float* qkv_w  = (const float*)d_in[1];   // [768,256]
    const float* proj_w = (const float*)d_in[2];   // [256,256]
    const float* proj_b = (const float*)d_in[3];   // [256]
    float* out = (float*)d_out;                    // [4,256,2048]

    // workspace: q_t 4MB | k_t 4MB | v 4MB | pre 8MB  (20MB total)
    char* ws = (char*)d_ws;
    ushort_t* q_t = (ushort_t*)(ws);
    ushort_t* k_t = (ushort_t*)(ws + (size_t)4  * 1024 * 1024);
    ushort_t* v_  = (ushort_t*)(ws + (size_t)8  * 1024 * 1024);
    float*    pre = (float*)   (ws + (size_t)12 * 1024 * 1024);

    qkv_gemm<<<dim3(QKVD/64, NTOK/64, 4), 256, 0, stream>>>(x, qkv_w, q_t, k_t, v_);
    attn_mfma<<<dim3(NTOK/128, 4 * HEADS), 256, 0, stream>>>(q_t, k_t, v_, pre);
    proj_gemm<<<dim3(CDIM/64, NTOK/64, 4), 256, 0, stream>>>(pre, proj_w, proj_b, out);
}

// Round 6
// 153.505 us; speedup vs baseline: 1.3757x; 1.3757x over previous
//
#include <hip/hip_runtime.h>
#include <hip/hip_bf16.h>

#define NTOK 2048
#define CDIM 256
#define HEADS 8
#define HD 32
#define SCALE 0.17677669529663687f  // 1/sqrt(32)

typedef __attribute__((ext_vector_type(8))) short short8;
typedef __attribute__((ext_vector_type(4))) float float4v;
typedef unsigned short ushort_t;
typedef unsigned int uint_t;

#define MFMA(a, b, c) __builtin_amdgcn_mfma_f32_16x16x32_bf16(a, b, c, 0, 0, 0)

__device__ __forceinline__ uint_t cvt_pk(float lo, float hi) {
    uint_t r;
    asm("v_cvt_pk_bf16_f32 %0, %1, %2" : "=v"(r) : "v"(lo), "v"(hi));
    return r;
}
__device__ __forceinline__ ushort_t f2bf(float f) {
    union { __hip_bfloat16 h; ushort_t u; } cv;
    cv.h = __float2bfloat16(f);   // RTNE
    return cv.u;
}

// ---------------- K0: f32 -> bf16 convert (8 elems/thread) ----------------
__global__ __launch_bounds__(256) void cvt_bf16(const float* __restrict__ in,
                                                uint4* __restrict__ out, int n8) {
    int i = blockIdx.x * 256 + threadIdx.x;
    if (i >= n8) return;
    const float4* p = (const float4*)in + (size_t)2 * i;
    float4 a = p[0], bq = p[1];
    uint4 r;
    r.x = cvt_pk(a.x, a.y);  r.y = cvt_pk(a.z, a.w);
    r.z = cvt_pk(bq.x, bq.y); r.w = cvt_pk(bq.z, bq.w);
    out[i] = r;
}

// ---------------- K1: qkv bf16 MFMA GEMM ----------------
// C[d][n] = sum_c w[d][c] * x[b][n][c]; both operands k-contig (A * B^T).
// 64x64 per wave, 4 waves (2x2) -> 128x128 block. grid (768/128, 2048/128, 4).
// Epilogue routes d = h*96+t: q_t[bh][n][t] (scaled), k_t[bh][n][t-32], v[bh][t-64][n].
__global__ __launch_bounds__(256) void qkv_mfma(const ushort_t* __restrict__ x_bf,
                                                const ushort_t* __restrict__ w_bf,
                                                ushort_t* __restrict__ q_t,
                                                ushort_t* __restrict__ k_t,
                                                ushort_t* __restrict__ v_) {
    const int tid = threadIdx.x, wave = tid >> 6, lane = tid & 63;
    const int l15 = lane & 15, g = lane >> 4;
    const int b = blockIdx.z;
    const int dtile = blockIdx.x * 128 + (wave >> 1) * 64;
    const int ntile = blockIdx.y * 128 + (wave & 1) * 64;

    const ushort_t* A = w_bf + (size_t)dtile * CDIM + g * 8;
    const ushort_t* B = x_bf + ((size_t)b * NTOK + ntile) * CDIM + g * 8;

    float4v acc[4][4];
    #pragma unroll
    for (int i = 0; i < 4; ++i)
        #pragma unroll
        for (int j = 0; j < 4; ++j)
            #pragma unroll
            for (int r = 0; r < 4; ++r) acc[i][j][r] = 0.f;

    #pragma unroll
    for (int k0 = 0; k0 < CDIM; k0 += 32) {
        short8 af[4], bf[4];
        #pragma unroll
        for (int i = 0; i < 4; ++i)
            af[i] = *(const short8*)&A[(size_t)(l15 + 16 * i) * CDIM + k0];
        #pragma unroll
        for (int j = 0; j < 4; ++j)
            bf[j] = *(const short8*)&B[(size_t)(l15 + 16 * j) * CDIM + k0];
        #pragma unroll
        for (int i = 0; i < 4; ++i)
            #pragma unroll
            for (int j = 0; j < 4; ++j)
                acc[i][j] = MFMA(af[i], bf[j], acc[i][j]);
    }

    #pragma unroll
    for (int i = 0; i < 4; ++i) {
        #pragma unroll
        for (int r = 0; r < 4; ++r) {
            const int d = dtile + i * 16 + g * 4 + r;
            const int h = (d * 683) >> 16;        // d/96 for d<768
            const int t = d - h * 96;
            const size_t bh = (size_t)(b * HEADS + h);
            #pragma unroll
            for (int j = 0; j < 4; ++j) {
                const int n = ntile + j * 16 + l15;
                const float val = acc[i][j][r];
                if (t < 64) {
                    const int sel = t >> 5, dm = t & 31;
                    ushort_t* dst = (sel ? k_t : q_t) + bh * ((size_t)NTOK * HD)
                                    + (size_t)n * HD + dm;
                    *dst = f2bf(sel ? val : val * SCALE);
                } else {
                    v_[bh * ((size_t)NTOK * HD) + (size_t)(t - 64) * NTOK + n] = f2bf(val);
                }
            }
        }
    }
}

// ---------------- K2: MFMA flash attention (no-max softmax, barrier-free) ----------------
// grid (2048/128, B*H), block 256 (4 independent waves, 32 queries each)
__global__ __launch_bounds__(256) void attn_mfma(const ushort_t* __restrict__ q_t,
                                                 const ushort_t* __restrict__ k_t,
                                                 const ushort_t* __restrict__ v_,
                                                 ushort_t* __restrict__ preT) {
    __shared__ uint_t pt[4][2][16 * 20];   // [wave][qs][16 rows x 80B]
    const int tid = threadIdx.x, wave = tid >> 6, lane = tid & 63;
    const int l15 = lane & 15, g = lane >> 4;
    const int bh = blockIdx.y, b = bh >> 3, h = bh & 7;
    const int j0 = blockIdx.x * 128 + wave * 32;

    const ushort_t* qb = q_t + (size_t)bh * (NTOK * HD);
    const ushort_t* kb = k_t + (size_t)bh * (NTOK * HD);
    const ushort_t* vb = v_  + (size_t)bh * (NTOK * HD);

    short8 qf0 = *(const short8*)&qb[(size_t)(j0 + l15) * HD + g * 8];
    short8 qf1 = *(const short8*)&qb[(size_t)(j0 + 16 + l15) * HD + g * 8];

    const float4v z4 = {0.f, 0.f, 0.f, 0.f};
    float4v o00 = z4, o01 = z4, o10 = z4, o11 = z4;   // o[dsub][qs]
    float lsum0 = 0.f, lsum1 = 0.f;

    uint_t* pt0 = &pt[wave][0][0];
    uint_t* pt1 = &pt[wave][1][0];
    const int wbase = l15 * 20 + g * 2;
    const int rbase = l15 * 20 + g * 4;

    for (int i0 = 0; i0 < NTOK; i0 += 32) {
        short8 aK0 = *(const short8*)&kb[(size_t)(i0 + l15) * HD + g * 8];
        short8 aK1 = *(const short8*)&kb[(size_t)(i0 + 16 + l15) * HD + g * 8];

        float4v s00 = MFMA(aK0, qf0, z4);
        float4v s10 = MFMA(aK1, qf0, z4);
        float4v s01 = MFMA(aK0, qf1, z4);
        float4v s11 = MFMA(aK1, qf1, z4);

        {
            float e0[4], e1[4];
            #pragma unroll
            for (int r = 0; r < 4; ++r) { e0[r] = __expf(s00[r]); e1[r] = __expf(s10[r]); }
            lsum0 += e0[0]+e0[1]+e0[2]+e0[3] + e1[0]+e1[1]+e1[2]+e1[3];
            pt0[wbase]     = cvt_pk(e0[0], e0[1]);
            pt0[wbase + 1] = cvt_pk(e0[2], e0[3]);
            pt0[wbase + 8] = cvt_pk(e1[0], e1[1]);
            pt0[wbase + 9] = cvt_pk(e1[2], e1[3]);
        }
        {
            float e0[4], e1[4];
            #pragma unroll
            for (int r = 0; r < 4; ++r) { e0[r] = __expf(s01[r]); e1[r] = __expf(s11[r]); }
            lsum1 += e0[0]+e0[1]+e0[2]+e0[3] + e1[0]+e1[1]+e1[2]+e1[3];
            pt1[wbase]     = cvt_pk(e0[0], e0[1]);
            pt1[wbase + 1] = cvt_pk(e0[2], e0[3]);
            pt1[wbase + 8] = cvt_pk(e1[0], e1[1]);
            pt1[wbase + 9] = cvt_pk(e1[2], e1[3]);
        }

        short8 pB0 = *(const short8*)&pt0[rbase];
        short8 pB1 = *(const short8*)&pt1[rbase];

        short8 aV0 = *(const short8*)&vb[(size_t)l15 * NTOK + i0 + g * 8];
        short8 aV1 = *(const short8*)&vb[(size_t)(16 + l15) * NTOK + i0 + g * 8];

        o00 = MFMA(aV0, pB0, o00);
        o01 = MFMA(aV0, pB1, o01);
        o10 = MFMA(aV1, pB0, o10);
        o11 = MFMA(aV1, pB1, o11);
    }

    lsum0 += __shfl_xor(lsum0, 16, 64); lsum0 += __shfl_xor(lsum0, 32, 64);
    lsum1 += __shfl_xor(lsum1, 16, 64); lsum1 += __shfl_xor(lsum1, 32, 64);
    const float rl0 = 1.f / lsum0, rl1 = 1.f / lsum1;

    // preT[b][n][c] bf16, c = h*32 + d_local
    ushort_t* pb_ = preT + ((size_t)b * NTOK + j0) * CDIM + h * HD;
    #pragma unroll
    for (int r = 0; r < 4; ++r) {
        const int d0 = g * 4 + r, d1 = 16 + g * 4 + r;
        pb_[(size_t)l15 * CDIM + d0]        = f2bf(o00[r] * rl0);
        pb_[(size_t)(16 + l15) * CDIM + d0] = f2bf(o01[r] * rl1);
        pb_[(size_t)l15 * CDIM + d1]        = f2bf(o10[r] * rl0);
        pb_[(size_t)(16 + l15) * CDIM + d1] = f2bf(o11[r] * rl1);
    }
}

// ---------------- K3: proj bf16 MFMA GEMM + bias ----------------
// out[b][dd][n] = sum_c w2[dd][c] * preT[b][n][c] + pb[dd]  (A * B^T, f32 out)
// grid (256/128, 2048/128, 4), block 256 (4 waves 2x2, 64x64 each)
__global__ __launch_bounds__(256) void proj_mfma(const ushort_t* __restrict__ preT,
                                                 const ushort_t* __restrict__ w2_bf,
                                                 const float* __restrict__ pb,
                                                 float* __restrict__ out) {
    const int tid = threadIdx.x, wave = tid >> 6, lane = tid & 63;
    const int l15 = lane & 15, g = lane >> 4;
    const int b = blockIdx.z;
    const int dtile = blockIdx.x * 128 + (wave >> 1) * 64;
    const int ntile = blockIdx.y * 128 + (wave & 1) * 64;

    const ushort_t* A = w2_bf + (size_t)dtile * CDIM + g * 8;
    const ushort_t* B = preT + ((size_t)b * NTOK + ntile) * CDIM + g * 8;

    float4v acc[4][4];
    #pragma unroll
    for (int i = 0; i < 4; ++i)
        #pragma unroll
        for (int j = 0; j < 4; ++j)
            #pragma unroll
            for (int r = 0; r < 4; ++r) acc[i][j][r] = 0.f;

    #pragma unroll
    for (int k0 = 0; k0 < CDIM; k0 += 32) {
        short8 af[4], bf[4];
        #pragma unroll
        for (int i = 0; i < 4; ++i)
            af[i] = *(const short8*)&A[(size_t)(l15 + 16 * i) * CDIM + k0];
        #pragma unroll
        for (int j = 0; j < 4; ++j)
            bf[j] = *(const short8*)&B[(size_t)(l15 + 16 * j) * CDIM + k0];
        #pragma unroll
        for (int i = 0; i < 4; ++i)
            #pragma unroll
            for (int j = 0; j < 4; ++j)
                acc[i][j] = MFMA(af[i], bf[j], acc[i][j]);
    }

    #pragma unroll
    for (int i = 0; i < 4; ++i) {
        #pragma unroll
        for (int r = 0; r < 4; ++r) {
            const int d = dtile + i * 16 + g * 4 + r;
            const float bias = pb[d];
            float* orow = out + ((size_t)b * CDIM + d) * NTOK + ntile;
            #pragma unroll
            for (int j = 0; j < 4; ++j)
                orow[j * 16 + l15] = acc[i][j][r] + bias;
        }
    }
}

extern "C" void kernel_launch(void* const* d_in, const int* in_sizes, int n_in,
                              void* d_out, int out_size, void* d_ws, size_t ws_size,
                              hipStream_t stream) {
    const float* x      = (const float*)d_in[0];   // [4,2048,256]
    const float* qkv_w  = (const float*)d_in[1];   // [768,256]
    const float* proj_w = (const float*)d_in[2];   // [256,256]
    const float* proj_b = (const float*)d_in[3];   // [256]
    float* out = (float*)d_out;                    // [4,256,2048]

    // ws: x_bf/preT alias 0-4MB | w_bf 4MB | w2_bf 4.5MB | q_t 5MB | k_t 9MB | v 13MB (17MB total)
    char* ws = (char*)d_ws;
    ushort_t* x_bf  = (ushort_t*)(ws);
    ushort_t* preT  = (ushort_t*)(ws);                                // alias: x_bf dead after qkv
    ushort_t* w_bf  = (ushort_t*)(ws + (size_t)4 * 1024 * 1024);
    ushort_t* w2_bf = (ushort_t*)(ws + (size_t)4608 * 1024);
    ushort_t* q_t   = (ushort_t*)(ws + (size_t)5 * 1024 * 1024);
    ushort_t* k_t   = (ushort_t*)(ws + (size_t)9 * 1024 * 1024);
    ushort_t* v_    = (ushort_t*)(ws + (size_t)13 * 1024 * 1024);

    cvt_bf16<<<1024, 256, 0, stream>>>(x,      (uint4*)x_bf,  262144);
    cvt_bf16<<<96,   256, 0, stream>>>(qkv_w,  (uint4*)w_bf,  24576);
    cvt_bf16<<<32,   256, 0, stream>>>(proj_w, (uint4*)w2_bf, 8192);
    qkv_mfma<<<dim3(6, 16, 4), 256, 0, stream>>>(x_bf, w_bf, q_t, k_t, v_);
    attn_mfma<<<dim3(NTOK / 128, 4 * HEADS), 256, 0, stream>>>(q_t, k_t, v_, preT);
    proj_mfma<<<dim3(2, 16, 4), 256, 0, stream>>>(preT, w2_bf, proj_b, out);
}

// Round 7
// 148.553 us; speedup vs baseline: 1.4215x; 1.0333x over previous
//
#include <hip/hip_runtime.h>
#include <hip/hip_bf16.h>

#define NTOK 2048
#define CDIM 256
#define HEADS 8
#define HD 32
#define SCALE 0.17677669529663687f  // 1/sqrt(32)

typedef __attribute__((ext_vector_type(8))) short short8;
typedef __attribute__((ext_vector_type(4))) float float4v;
typedef unsigned short ushort_t;
typedef unsigned int uint_t;

#define MFMA(a, b, c) __builtin_amdgcn_mfma_f32_16x16x32_bf16(a, b, c, 0, 0, 0)

__device__ __forceinline__ uint_t cvt_pk(float lo, float hi) {
    uint_t r;
    asm("v_cvt_pk_bf16_f32 %0, %1, %2" : "=v"(r) : "v"(lo), "v"(hi));
    return r;
}
__device__ __forceinline__ ushort_t f2bf(float f) {
    union { __hip_bfloat16 h; ushort_t u; } cv;
    cv.h = __float2bfloat16(f);   // RTNE
    return cv.u;
}

// ---------------- K0: f32 -> bf16 convert (8 elems/thread) ----------------
__global__ __launch_bounds__(256) void cvt_bf16(const float* __restrict__ in,
                                                uint4* __restrict__ out, int n8) {
    int i = blockIdx.x * 256 + threadIdx.x;
    if (i >= n8) return;
    const float4* p = (const float4*)in + (size_t)2 * i;
    float4 a = p[0], bq = p[1];
    uint4 r;
    r.x = cvt_pk(a.x, a.y);  r.y = cvt_pk(a.z, a.w);
    r.z = cvt_pk(bq.x, bq.y); r.w = cvt_pk(bq.z, bq.w);
    out[i] = r;
}

// ---------------- K1: qkv bf16 MFMA GEMM, 32x64 per wave ----------------
// C[d][n] = sum_c w[d][c] * x[b][n][c]  (A * B^T, both k-contig)
// 4 waves 2x2 -> block tile 64x128. grid (768/64, 2048/128, 4) = 768 blocks, 3072 waves.
// 32-row d-tiles align with the 96-row head period -> each wave is purely q, k, or v.
__global__ __launch_bounds__(256) void qkv_mfma(const ushort_t* __restrict__ x_bf,
                                                const ushort_t* __restrict__ w_bf,
                                                ushort_t* __restrict__ q_t,
                                                ushort_t* __restrict__ k_t,
                                                ushort_t* __restrict__ v_) {
    const int tid = threadIdx.x, wave = tid >> 6, lane = tid & 63;
    const int l15 = lane & 15, g = lane >> 4;
    const int b = blockIdx.z;
    const int dtile = blockIdx.x * 64 + (wave >> 1) * 32;
    const int ntile = blockIdx.y * 128 + (wave & 1) * 64;

    const ushort_t* A = w_bf + (size_t)dtile * CDIM + g * 8;
    const ushort_t* B = x_bf + ((size_t)b * NTOK + ntile) * CDIM + g * 8;

    float4v acc[2][4];
    #pragma unroll
    for (int i = 0; i < 2; ++i)
        #pragma unroll
        for (int j = 0; j < 4; ++j)
            #pragma unroll
            for (int r = 0; r < 4; ++r) acc[i][j][r] = 0.f;

    #pragma unroll
    for (int k0 = 0; k0 < CDIM; k0 += 32) {
        short8 af[2], bf[4];
        #pragma unroll
        for (int i = 0; i < 2; ++i)
            af[i] = *(const short8*)&A[(size_t)(l15 + 16 * i) * CDIM + k0];
        #pragma unroll
        for (int j = 0; j < 4; ++j)
            bf[j] = *(const short8*)&B[(size_t)(l15 + 16 * j) * CDIM + k0];
        #pragma unroll
        for (int i = 0; i < 2; ++i)
            #pragma unroll
            for (int j = 0; j < 4; ++j)
                acc[i][j] = MFMA(af[i], bf[j], acc[i][j]);
    }

    const int hq = (dtile * 683) >> 16;     // dtile/96 (wave-uniform)
    const int tl = dtile - hq * 96;         // 0 (=q), 32 (=k), 64 (=v)
    const size_t bh = (size_t)(b * HEADS + hq);

    if (tl == 64) {
        // v[bh][dloc][n], n-fast
        #pragma unroll
        for (int i = 0; i < 2; ++i)
            #pragma unroll
            for (int j = 0; j < 4; ++j)
                #pragma unroll
                for (int r = 0; r < 4; ++r)
                    v_[bh * ((size_t)NTOK * HD) + (size_t)(i * 16 + g * 4 + r) * NTOK
                       + ntile + j * 16 + l15] = f2bf(acc[i][j][r]);
    } else {
        // q_t / k_t [bh][n][dloc], d-fast: pack 4 contiguous bf16 per (i,j)
        ushort_t* base = (tl ? k_t : q_t) + bh * ((size_t)NTOK * HD);
        const float mul = tl ? 1.f : SCALE;
        #pragma unroll
        for (int i = 0; i < 2; ++i)
            #pragma unroll
            for (int j = 0; j < 4; ++j) {
                uint2 pk;
                pk.x = cvt_pk(acc[i][j][0] * mul, acc[i][j][1] * mul);
                pk.y = cvt_pk(acc[i][j][2] * mul, acc[i][j][3] * mul);
                *(uint2*)&base[(size_t)(ntile + j * 16 + l15) * HD + i * 16 + g * 4] = pk;
            }
    }
}

// ---------------- K2: MFMA flash attention, key-split x2 ----------------
// Block 256 = 4 waves: wave>>1 = query subtile (32 q), wave&1 = key half (1024 keys).
// Partner waves combine unnormalized O + sum(exp) via LDS.
// grid (BH=32, 2048/64) -- bh on x so bh == XCD (mod 8): K/V stay L2-local.
__global__ __launch_bounds__(256) void attn_mfma(const ushort_t* __restrict__ q_t,
                                                 const ushort_t* __restrict__ k_t,
                                                 const ushort_t* __restrict__ v_,
                                                 ushort_t* __restrict__ preT) {
    __shared__ uint_t pt[4][2][16 * 20];     // [wave][qs][16 rows x 80B] P^T
    __shared__ float comb[4][64][18];        // partial O (16) + lsum (2)
    const int tid = threadIdx.x, wave = tid >> 6, lane = tid & 63;
    const int l15 = lane & 15, g = lane >> 4;
    const int bh = blockIdx.x, b = bh >> 3, h = bh & 7;
    const int j0 = blockIdx.y * 64 + (wave >> 1) * 32;
    const int khalf = wave & 1;

    const ushort_t* qb = q_t + (size_t)bh * (NTOK * HD);
    const ushort_t* kb = k_t + (size_t)bh * (NTOK * HD);
    const ushort_t* vb = v_  + (size_t)bh * (NTOK * HD);

    short8 qf0 = *(const short8*)&qb[(size_t)(j0 + l15) * HD + g * 8];
    short8 qf1 = *(const short8*)&qb[(size_t)(j0 + 16 + l15) * HD + g * 8];

    const float4v z4 = {0.f, 0.f, 0.f, 0.f};
    float4v o00 = z4, o01 = z4, o10 = z4, o11 = z4;   // o[dsub][qs] (unnormalized)
    float lsum0 = 0.f, lsum1 = 0.f;

    uint_t* pt0 = &pt[wave][0][0];
    uint_t* pt1 = &pt[wave][1][0];
    const int wbase = l15 * 20 + g * 2;
    const int rbase = l15 * 20 + g * 4;

    const int kbeg = khalf * 1024, kend = kbeg + 1024;
    for (int i0 = kbeg; i0 < kend; i0 += 32) {
        short8 aK0 = *(const short8*)&kb[(size_t)(i0 + l15) * HD + g * 8];
        short8 aK1 = *(const short8*)&kb[(size_t)(i0 + 16 + l15) * HD + g * 8];

        float4v s00 = MFMA(aK0, qf0, z4);
        float4v s10 = MFMA(aK1, qf0, z4);
        float4v s01 = MFMA(aK0, qf1, z4);
        float4v s11 = MFMA(aK1, qf1, z4);

        {
            float e0[4], e1[4];
            #pragma unroll
            for (int r = 0; r < 4; ++r) { e0[r] = __expf(s00[r]); e1[r] = __expf(s10[r]); }
            lsum0 += e0[0]+e0[1]+e0[2]+e0[3] + e1[0]+e1[1]+e1[2]+e1[3];
            pt0[wbase]     = cvt_pk(e0[0], e0[1]);
            pt0[wbase + 1] = cvt_pk(e0[2], e0[3]);
            pt0[wbase + 8] = cvt_pk(e1[0], e1[1]);
            pt0[wbase + 9] = cvt_pk(e1[2], e1[3]);
        }
        {
            float e0[4], e1[4];
            #pragma unroll
            for (int r = 0; r < 4; ++r) { e0[r] = __expf(s01[r]); e1[r] = __expf(s11[r]); }
            lsum1 += e0[0]+e0[1]+e0[2]+e0[3] + e1[0]+e1[1]+e1[2]+e1[3];
            pt1[wbase]     = cvt_pk(e0[0], e0[1]);
            pt1[wbase + 1] = cvt_pk(e0[2], e0[3]);
            pt1[wbase + 8] = cvt_pk(e1[0], e1[1]);
            pt1[wbase + 9] = cvt_pk(e1[2], e1[3]);
        }

        short8 pB0 = *(const short8*)&pt0[rbase];
        short8 pB1 = *(const short8*)&pt1[rbase];

        short8 aV0 = *(const short8*)&vb[(size_t)l15 * NTOK + i0 + g * 8];
        short8 aV1 = *(const short8*)&vb[(size_t)(16 + l15) * NTOK + i0 + g * 8];

        o00 = MFMA(aV0, pB0, o00);
        o01 = MFMA(aV0, pB1, o01);
        o10 = MFMA(aV1, pB0, o10);
        o11 = MFMA(aV1, pB1, o11);
    }

    // reduce lsum across the 4 lane-groups within the wave
    lsum0 += __shfl_xor(lsum0, 16, 64); lsum0 += __shfl_xor(lsum0, 32, 64);
    lsum1 += __shfl_xor(lsum1, 16, 64); lsum1 += __shfl_xor(lsum1, 32, 64);

    // cross-wave combine (key halves)
    float* cb = &comb[wave][lane][0];
    #pragma unroll
    for (int r = 0; r < 4; ++r) {
        cb[r] = o00[r]; cb[4 + r] = o01[r]; cb[8 + r] = o10[r]; cb[12 + r] = o11[r];
    }
    cb[16] = lsum0; cb[17] = lsum1;
    __syncthreads();

    if (khalf == 0) {
        const float* cp = &comb[wave ^ 1][lane][0];
        #pragma unroll
        for (int r = 0; r < 4; ++r) {
            o00[r] += cp[r]; o01[r] += cp[4 + r]; o10[r] += cp[8 + r]; o11[r] += cp[12 + r];
        }
        const float rl0 = 1.f / (lsum0 + cp[16]);
        const float rl1 = 1.f / (lsum1 + cp[17]);

        // preT[b][n][c] bf16, c = h*32 + dloc; pack 4 contiguous c per store
        ushort_t* pb_ = preT + ((size_t)b * NTOK + j0) * CDIM + h * HD;
        uint2 w0, w1, w2, w3;
        w0.x = cvt_pk(o00[0] * rl0, o00[1] * rl0); w0.y = cvt_pk(o00[2] * rl0, o00[3] * rl0);
        w1.x = cvt_pk(o01[0] * rl1, o01[1] * rl1); w1.y = cvt_pk(o01[2] * rl1, o01[3] * rl1);
        w2.x = cvt_pk(o10[0] * rl0, o10[1] * rl0); w2.y = cvt_pk(o10[2] * rl0, o10[3] * rl0);
        w3.x = cvt_pk(o11[0] * rl1, o11[1] * rl1); w3.y = cvt_pk(o11[2] * rl1, o11[3] * rl1);
        *(uint2*)&pb_[(size_t)l15 * CDIM + g * 4] = w0;
        *(uint2*)&pb_[(size_t)(16 + l15) * CDIM + g * 4] = w1;
        *(uint2*)&pb_[(size_t)l15 * CDIM + 16 + g * 4] = w2;
        *(uint2*)&pb_[(size_t)(16 + l15) * CDIM + 16 + g * 4] = w3;
    }
}

// ---------------- K3: proj bf16 MFMA GEMM + bias, 32x32 per wave ----------------
// out[b][dd][n] = sum_c w2[dd][c] * preT[b][n][c] + pb[dd]
// 4 waves 2x2 -> 64x64 block. grid (4, 32, 4) = 512 blocks, 2048 waves.
__global__ __launch_bounds__(256) void proj_mfma(const ushort_t* __restrict__ preT,
                                                 const ushort_t* __restrict__ w2_bf,
                                                 const float* __restrict__ pb,
                                                 float* __restrict__ out) {
    const int tid = threadIdx.x, wave = tid >> 6, lane = tid & 63;
    const int l15 = lane & 15, g = lane >> 4;
    const int b = blockIdx.z;
    const int dtile = blockIdx.x * 64 + (wave >> 1) * 32;
    const int ntile = blockIdx.y * 64 + (wave & 1) * 32;

    const ushort_t* A = w2_bf + (size_t)dtile * CDIM + g * 8;
    const ushort_t* B = preT + ((size_t)b * NTOK + ntile) * CDIM + g * 8;

    float4v acc[2][2];
    #pragma unroll
    for (int i = 0; i < 2; ++i)
        #pragma unroll
        for (int j = 0; j < 2; ++j)
            #pragma unroll
            for (int r = 0; r < 4; ++r) acc[i][j][r] = 0.f;

    #pragma unroll
    for (int k0 = 0; k0 < CDIM; k0 += 32) {
        short8 af[2], bf[2];
        #pragma unroll
        for (int i = 0; i < 2; ++i)
            af[i] = *(const short8*)&A[(size_t)(l15 + 16 * i) * CDIM + k0];
        #pragma unroll
        for (int j = 0; j < 2; ++j)
            bf[j] = *(const short8*)&B[(size_t)(l15 + 16 * j) * CDIM + k0];
        #pragma unroll
        for (int i = 0; i < 2; ++i)
            #pragma unroll
            for (int j = 0; j < 2; ++j)
                acc[i][j] = MFMA(af[i], bf[j], acc[i][j]);
    }

    #pragma unroll
    for (int i = 0; i < 2; ++i) {
        #pragma unroll
        for (int r = 0; r < 4; ++r) {
            const int d = dtile + i * 16 + g * 4 + r;
            const float bias = pb[d];
            float* orow = out + ((size_t)b * CDIM + d) * NTOK + ntile;
            #pragma unroll
            for (int j = 0; j < 2; ++j)
                orow[j * 16 + l15] = acc[i][j][r] + bias;
        }
    }
}

extern "C" void kernel_launch(void* const* d_in, const int* in_sizes, int n_in,
                              void* d_out, int out_size, void* d_ws, size_t ws_size,
                              hipStream_t stream) {
    const float* x      = (const float*)d_in[0];   // [4,2048,256]
    const float* qkv_w  = (const float*)d_in[1];   // [768,256]
    const float* proj_w = (const float*)d_in[2];   // [256,256]
    const float* proj_b = (const float*)d_in[3];   // [256]
    float* out = (float*)d_out;                    // [4,256,2048]

    // ws: x_bf/preT alias 0-4MB | w_bf 4MB | w2_bf 4.5MB | q_t 5MB | k_t 9MB | v 13MB (17MB)
    char* ws = (char*)d_ws;
    ushort_t* x_bf  = (ushort_t*)(ws);
    ushort_t* preT  = (ushort_t*)(ws);                  // alias: x_bf dead after qkv
    ushort_t* w_bf  = (ushort_t*)(ws + (size_t)4 * 1024 * 1024);
    ushort_t* w2_bf = (ushort_t*)(ws + (size_t)4608 * 1024);
    ushort_t* q_t   = (ushort_t*)(ws + (size_t)5 * 1024 * 1024);
    ushort_t* k_t   = (ushort_t*)(ws + (size_t)9 * 1024 * 1024);
    ushort_t* v_    = (ushort_t*)(ws + (size_t)13 * 1024 * 1024);

    cvt_bf16<<<1024, 256, 0, stream>>>(x,      (uint4*)x_bf,  262144);
    cvt_bf16<<<96,   256, 0, stream>>>(qkv_w,  (uint4*)w_bf,  24576);
    cvt_bf16<<<32,   256, 0, stream>>>(proj_w, (uint4*)w2_bf, 8192);
    qkv_mfma<<<dim3(12, 16, 4), 256, 0, stream>>>(x_bf, w_bf, q_t, k_t, v_);
    attn_mfma<<<dim3(4 * HEADS, NTOK / 64), 256, 0, stream>>>(q_t, k_t, v_, preT);
    proj_mfma<<<dim3(4, 32, 4), 256, 0, stream>>>(preT, w2_bf, proj_b, out);
}

// Round 10
// 144.753 us; speedup vs baseline: 1.4588x; 1.0262x over previous
//
#include <hip/hip_runtime.h>
#include <hip/hip_bf16.h>

#define NTOK 2048
#define CDIM 256
#define HEADS 8
#define HD 32
// q scale: (1/sqrt(32)) * log2(e)  -> softmax exp becomes exp2
#define QSC 0.25505480068568306f

typedef __attribute__((ext_vector_type(8))) short short8;
typedef __attribute__((ext_vector_type(4))) float float4v;
typedef unsigned short ushort_t;
typedef unsigned int uint_t;

#define MFMA(a, b, c) __builtin_amdgcn_mfma_f32_16x16x32_bf16(a, b, c, 0, 0, 0)

__device__ __forceinline__ uint_t cvt_pk(float lo, float hi) {
    uint_t r;
    asm("v_cvt_pk_bf16_f32 %0, %1, %2" : "=v"(r) : "v"(lo), "v"(hi));
    return r;
}
__device__ __forceinline__ ushort_t f2bf(float f) {
    union { __hip_bfloat16 h; ushort_t u; } cv;
    cv.h = __float2bfloat16(f);   // RTNE
    return cv.u;
}
#if __has_builtin(__builtin_amdgcn_exp2f)
#define EXP2(x) __builtin_amdgcn_exp2f(x)
#else
#define EXP2(x) exp2f(x)
#endif

// ---------------- K0: all three f32 -> bf16 converts in one launch ----------------
// blocks [0,1024): x (262144 x8); [1024,1120): qkv_w (24576); [1120,1152): proj_w (8192)
__global__ __launch_bounds__(256) void cvt_all(const float* __restrict__ x,
                                               const float* __restrict__ w,
                                               const float* __restrict__ w2,
                                               uint4* __restrict__ xo,
                                               uint4* __restrict__ wo,
                                               uint4* __restrict__ w2o) {
    const int bid = blockIdx.x;
    const float* in; uint4* out; int i;
    if (bid < 1024)      { in = x;  out = xo;  i = bid * 256 + threadIdx.x; }
    else if (bid < 1120) { in = w;  out = wo;  i = (bid - 1024) * 256 + threadIdx.x; }
    else                 { in = w2; out = w2o; i = (bid - 1120) * 256 + threadIdx.x; }
    const float4* p = (const float4*)in + (size_t)2 * i;
    float4 a = p[0], bq = p[1];
    uint4 r;
    r.x = cvt_pk(a.x, a.y);   r.y = cvt_pk(a.z, a.w);
    r.z = cvt_pk(bq.x, bq.y); r.w = cvt_pk(bq.z, bq.w);
    out[i] = r;
}

// ---------------- K1: qkv bf16 MFMA GEMM, 32x64/wave, LDS-bounced epilogue ----------------
// C[d][n] = sum_c w[d][c] * x[b][n][c]. grid (12, 16, 4), block 256.
// 32-row d-tiles align with the 96-row head period -> wave is purely q, k, or v.
// Epilogue transposes through per-wave LDS so all global stores are coalesced dwordx4.
__global__ __launch_bounds__(256) void qkv_mfma(const ushort_t* __restrict__ x_bf,
                                                const ushort_t* __restrict__ w_bf,
                                                ushort_t* __restrict__ q_t,
                                                ushort_t* __restrict__ k_t,
                                                ushort_t* __restrict__ v_) {
    __shared__ ushort_t lds[4][2048];
    const int tid = threadIdx.x, wave = tid >> 6, lane = tid & 63;
    const int l15 = lane & 15, g = lane >> 4;
    const int b = blockIdx.z;
    const int dtile = blockIdx.x * 64 + (wave >> 1) * 32;
    const int ntile = blockIdx.y * 128 + (wave & 1) * 64;

    const ushort_t* A = w_bf + (size_t)dtile * CDIM + g * 8;
    const ushort_t* B = x_bf + ((size_t)b * NTOK + ntile) * CDIM + g * 8;

    float4v acc[2][4];
    #pragma unroll
    for (int i = 0; i < 2; ++i)
        #pragma unroll
        for (int j = 0; j < 4; ++j)
            #pragma unroll
            for (int r = 0; r < 4; ++r) acc[i][j][r] = 0.f;

    #pragma unroll
    for (int k0 = 0; k0 < CDIM; k0 += 32) {
        short8 af[2], bf[4];
        #pragma unroll
        for (int i = 0; i < 2; ++i)
            af[i] = *(const short8*)&A[(size_t)(l15 + 16 * i) * CDIM + k0];
        #pragma unroll
        for (int j = 0; j < 4; ++j)
            bf[j] = *(const short8*)&B[(size_t)(l15 + 16 * j) * CDIM + k0];
        #pragma unroll
        for (int i = 0; i < 2; ++i)
            #pragma unroll
            for (int j = 0; j < 4; ++j)
                acc[i][j] = MFMA(af[i], bf[j], acc[i][j]);
    }

    const int hq = (dtile * 683) >> 16;     // dtile/96 (wave-uniform)
    const int tl = dtile - hq * 96;         // 0 (=q), 32 (=k), 64 (=v)
    const size_t bh = (size_t)(b * HEADS + hq);
    ushort_t* W = lds[wave];

    if (tl == 64) {
        // --- v[bh][dloc][n] n-fast.  LDS tile [32 d][64 n], 16B-chunk XOR swizzle.
        #pragma unroll
        for (int i = 0; i < 2; ++i)
            #pragma unroll
            for (int j = 0; j < 4; ++j) {
                const int c = j * 2 + (l15 >> 3);        // 8-elem chunk 0..7
                #pragma unroll
                for (int r = 0; r < 4; ++r) {
                    const int d = i * 16 + g * 4 + r;
                    W[d * 64 + ((c ^ (d & 7)) * 8) + (l15 & 7)] = f2bf(acc[i][j][r]);
                }
            }
        ushort_t* vb = v_ + bh * ((size_t)NTOK * HD);
        #pragma unroll
        for (int t = 0; t < 4; ++t) {
            const int d = t * 8 + (lane >> 3), c = lane & 7;
            uint4 val = *(const uint4*)&W[d * 64 + ((c ^ (d & 7)) * 8)];
            *(uint4*)&vb[(size_t)d * NTOK + ntile + c * 8] = val;
        }
    } else {
        // --- q_t / k_t [bh][n][dloc] d-fast.  LDS tile [64 n][32 d], 16B-chunk XOR swizzle.
        ushort_t* base = (tl ? k_t : q_t) + bh * ((size_t)NTOK * HD);
        const float mul = tl ? 1.f : QSC;
        #pragma unroll
        for (int i = 0; i < 2; ++i)
            #pragma unroll
            for (int j = 0; j < 4; ++j) {
                uint2 pk;
                pk.x = cvt_pk(acc[i][j][0] * mul, acc[i][j][1] * mul);
                pk.y = cvt_pk(acc[i][j][2] * mul, acc[i][j][3] * mul);
                const int row = j * 16 + l15;            // n-local 0..63
                const int c16 = i * 2 + (g >> 1);        // 8-elem chunk 0..3
                *(uint2*)&W[row * 32 + ((c16 ^ (row & 3)) * 8) + (g & 1) * 4] = pk;
            }
        #pragma unroll
        for (int t = 0; t < 4; ++t) {
            const int row = t * 16 + (lane >> 2), c = lane & 3;
            uint4 val = *(const uint4*)&W[row * 32 + ((c ^ (row & 3)) * 8)];
            *(uint4*)&base[(size_t)(ntile + row) * HD + c * 8] = val;
        }
    }
}

// ---------------- K2: MFMA flash attention, key-split x2, exp2 + MFMA-lsum ----------------
// Block 256 = 4 waves: wave>>1 = query subtile (32 q), wave&1 = key half (1024 keys).
// grid (BH=32, 2048/64) -- bh on x so bh == XCD (mod 8): K/V stay L2-local.
__global__ __launch_bounds__(256) void attn_mfma(const ushort_t* __restrict__ q_t,
                                                 const ushort_t* __restrict__ k_t,
                                                 const ushort_t* __restrict__ v_,
                                                 ushort_t* __restrict__ preT) {
    // per-wave 1152 floats: P^T scratch (640 u32) aliased with combine buffer (64x18 f32)
    __shared__ float smem[4][1152];
    const int tid = threadIdx.x, wave = tid >> 6, lane = tid & 63;
    const int l15 = lane & 15, g = lane >> 4;
    const int bh = blockIdx.x, b = bh >> 3, h = bh & 7;
    const int j0 = blockIdx.y * 64 + (wave >> 1) * 32;
    const int khalf = wave & 1;

    const ushort_t* qb = q_t + (size_t)bh * (NTOK * HD);
    const ushort_t* kb = k_t + (size_t)bh * (NTOK * HD);
    const ushort_t* vb = v_  + (size_t)bh * (NTOK * HD);

    short8 qf0 = *(const short8*)&qb[(size_t)(j0 + l15) * HD + g * 8];
    short8 qf1 = *(const short8*)&qb[(size_t)(j0 + 16 + l15) * HD + g * 8];

    short8 ones;
    #pragma unroll
    for (int r = 0; r < 8; ++r) ones[r] = (short)0x3F80;   // bf16 1.0

    const float4v z4 = {0.f, 0.f, 0.f, 0.f};
    float4v o00 = z4, o01 = z4, o10 = z4, o11 = z4;   // unnormalized O
    float4v lacc0 = z4, lacc1 = z4;                   // column sums of P via MFMA(ones,P)

    float* myb = smem[wave];
    uint_t* pt0 = (uint_t*)myb;
    uint_t* pt1 = (uint_t*)myb + 320;
    const int wbase = l15 * 20 + g * 2;
    const int rbase = l15 * 20 + g * 4;

    const int kbeg = khalf * 1024, kend = kbeg + 1024;
    short8 aK0 = *(const short8*)&kb[(size_t)(kbeg + l15) * HD + g * 8];
    short8 aK1 = *(const short8*)&kb[(size_t)(kbeg + 16 + l15) * HD + g * 8];
    short8 aV0 = *(const short8*)&vb[(size_t)l15 * NTOK + kbeg + g * 8];
    short8 aV1 = *(const short8*)&vb[(size_t)(16 + l15) * NTOK + kbeg + g * 8];

    for (int i0 = kbeg; i0 < kend; i0 += 32) {
        const int ip = (i0 + 32 < kend) ? i0 + 32 : kbeg;   // prefetch (wrap = safe addr)
        short8 nK0 = *(const short8*)&kb[(size_t)(ip + l15) * HD + g * 8];
        short8 nK1 = *(const short8*)&kb[(size_t)(ip + 16 + l15) * HD + g * 8];
        short8 nV0 = *(const short8*)&vb[(size_t)l15 * NTOK + ip + g * 8];
        short8 nV1 = *(const short8*)&vb[(size_t)(16 + l15) * NTOK + ip + g * 8];

        float4v s00 = MFMA(aK0, qf0, z4);
        float4v s10 = MFMA(aK1, qf0, z4);
        float4v s01 = MFMA(aK0, qf1, z4);
        float4v s11 = MFMA(aK1, qf1, z4);

        uint2 w0, w1;
        w0.x = cvt_pk(EXP2(s00[0]), EXP2(s00[1]));
        w0.y = cvt_pk(EXP2(s00[2]), EXP2(s00[3]));
        w1.x = cvt_pk(EXP2(s10[0]), EXP2(s10[1]));
        w1.y = cvt_pk(EXP2(s10[2]), EXP2(s10[3]));
        *(uint2*)&pt0[wbase]     = w0;
        *(uint2*)&pt0[wbase + 8] = w1;
        w0.x = cvt_pk(EXP2(s01[0]), EXP2(s01[1]));
        w0.y = cvt_pk(EXP2(s01[2]), EXP2(s01[3]));
        w1.x = cvt_pk(EXP2(s11[0]), EXP2(s11[1]));
        w1.y = cvt_pk(EXP2(s11[2]), EXP2(s11[3]));
        *(uint2*)&pt1[wbase]     = w0;
        *(uint2*)&pt1[wbase + 8] = w1;

        short8 pB0 = *(const short8*)&pt0[rbase];
        short8 pB1 = *(const short8*)&pt1[rbase];

        lacc0 = MFMA(ones, pB0, lacc0);
        lacc1 = MFMA(ones, pB1, lacc1);
        o00 = MFMA(aV0, pB0, o00);
        o01 = MFMA(aV0, pB1, o01);
        o10 = MFMA(aV1, pB0, o10);
        o11 = MFMA(aV1, pB1, o11);

        aK0 = nK0; aK1 = nK1; aV0 = nV0; aV1 = nV1;
    }

    // cross-wave combine (key halves). comb region aliases pt (dead after last pB read).
    float* dst = &myb[lane * 18];
    #pragma unroll
    for (int r = 0; r < 4; ++r) {
        dst[r] = o00[r]; dst[4 + r] = o01[r]; dst[8 + r] = o10[r]; dst[12 + r] = o11[r];
    }
    dst[16] = lacc0[0]; dst[17] = lacc1[0];
    __syncthreads();

    if (khalf == 0) {
        const float* cp = &smem[wave ^ 1][lane * 18];
        #pragma unroll
        for (int r = 0; r < 4; ++r) {
            o00[r] += cp[r]; o01[r] += cp[4 + r]; o10[r] += cp[8 + r]; o11[r] += cp[12 + r];
        }
        const float rl0 = 1.f / (lacc0[0] + cp[16]);
        const float rl1 = 1.f / (lacc1[0] + cp[17]);

        ushort_t* pb_ = preT + ((size_t)b * NTOK + j0) * CDIM + h * HD;
        uint2 w0, w1, w2, w3;
        w0.x = cvt_pk(o00[0] * rl0, o00[1] * rl0); w0.y = cvt_pk(o00[2] * rl0, o00[3] * rl0);
        w1.x = cvt_pk(o01[0] * rl1, o01[1] * rl1); w1.y = cvt_pk(o01[2] * rl1, o01[3] * rl1);
        w2.x = cvt_pk(o10[0] * rl0, o10[1] * rl0); w2.y = cvt_pk(o10[2] * rl0, o10[3] * rl0);
        w3.x = cvt_pk(o11[0] * rl1, o11[1] * rl1); w3.y = cvt_pk(o11[2] * rl1, o11[3] * rl1);
        *(uint2*)&pb_[(size_t)l15 * CDIM + g * 4] = w0;
        *(uint2*)&pb_[(size_t)(16 + l15) * CDIM + g * 4] = w1;
        *(uint2*)&pb_[(size_t)l15 * CDIM + 16 + g * 4] = w2;
        *(uint2*)&pb_[(size_t)(16 + l15) * CDIM + 16 + g * 4] = w3;
    }
}

// ---------------- K3: proj bf16 MFMA GEMM + bias, 32x32/wave ----------------
// out[b][dd][n] = sum_c w2[dd][c] * preT[b][n][c] + pb[dd].  grid (4, 32, 4).
__global__ __launch_bounds__(256) void proj_mfma(const ushort_t* __restrict__ preT,
                                                 const ushort_t* __restrict__ w2_bf,
                                                 const float* __restrict__ pb,
                                                 float* __restrict__ out) {
    const int tid = threadIdx.x, wave = tid >> 6, lane = tid & 63;
    const int l15 = lane & 15, g = lane >> 4;
    const int b = blockIdx.z;
    const int dtile = blockIdx.x * 64 + (wave >> 1) * 32;
    const int ntile = blockIdx.y * 64 + (wave & 1) * 32;

    const ushort_t* A = w2_bf + (size_t)dtile * CDIM + g * 8;
    const ushort_t* B = preT + ((size_t)b * NTOK + ntile) * CDIM + g * 8;

    float4v acc[2][2];
    #pragma unroll
    for (int i = 0; i < 2; ++i)
        #pragma unroll
        for (int j = 0; j < 2; ++j)
            #pragma unroll
            for (int r = 0; r < 4; ++r) acc[i][j][r] = 0.f;

    #pragma unroll
    for (int k0 = 0; k0 < CDIM; k0 += 32) {
        short8 af[2], bf[2];
        #pragma unroll
        for (int i = 0; i < 2; ++i)
            af[i] = *(const short8*)&A[(size_t)(l15 + 16 * i) * CDIM + k0];
        #pragma unroll
        for (int j = 0; j < 2; ++j)
            bf[j] = *(const short8*)&B[(size_t)(l15 + 16 * j) * CDIM + k0];
        #pragma unroll
        for (int i = 0; i < 2; ++i)
            #pragma unroll
            for (int j = 0; j < 2; ++j)
                acc[i][j] = MFMA(af[i], bf[j], acc[i][j]);
    }

    #pragma unroll
    for (int i = 0; i < 2; ++i) {
        #pragma unroll
        for (int r = 0; r < 4; ++r) {
            const int d = dtile + i * 16 + g * 4 + r;
            const float bias = pb[d];
            float* orow = out + ((size_t)b * CDIM + d) * NTOK + ntile;
            #pragma unroll
            for (int j = 0; j < 2; ++j)
                orow[j * 16 + l15] = acc[i][j][r] + bias;
        }
    }
}

extern "C" void kernel_launch(void* const* d_in, const int* in_sizes, int n_in,
                              void* d_out, int out_size, void* d_ws, size_t ws_size,
                              hipStream_t stream) {
    const float* x      = (const float*)d_in[0];   // [4,2048,256]
    const float* qkv_w  = (const float*)d_in[1];   // [768,256]
    const float* proj_w = (const float*)d_in[2];   // [256,256]
    const float* proj_b = (const float*)d_in[3];   // [256]
    float* out = (float*)d_out;                    // [4,256,2048]

    // ws: x_bf/preT alias 0-4MB | w_bf 4MB | w2_bf 4.5MB | q_t 5MB | k_t 9MB | v 13MB (17MB)
    char* ws = (char*)d_ws;
    ushort_t* x_bf  = (ushort_t*)(ws);
    ushort_t* preT  = (ushort_t*)(ws);                  // alias: x_bf dead after qkv
    ushort_t* w_bf  = (ushort_t*)(ws + (size_t)4 * 1024 * 1024);
    ushort_t* w2_bf = (ushort_t*)(ws + (size_t)4608 * 1024);
    ushort_t* q_t   = (ushort_t*)(ws + (size_t)5 * 1024 * 1024);
    ushort_t* k_t   = (ushort_t*)(ws + (size_t)9 * 1024 * 1024);
    ushort_t* v_    = (ushort_t*)(ws + (size_t)13 * 1024 * 1024);

    cvt_all<<<1152, 256, 0, stream>>>(x, qkv_w, proj_w,
                                      (uint4*)x_bf, (uint4*)w_bf, (uint4*)w2_bf);
    qkv_mfma<<<dim3(12, 16, 4), 256, 0, stream>>>(x_bf, w_bf, q_t, k_t, v_);
    attn_mfma<<<dim3(4 * HEADS, NTOK / 64), 256, 0, stream>>>(q_t, k_t, v_, preT);
    proj_mfma<<<dim3(4, 32, 4), 256, 0, stream>>>(preT, w2_bf, proj_b, out);
}

// Round 13
// 144.322 us; speedup vs baseline: 1.4632x; 1.0030x over previous
//
#include <hip/hip_runtime.h>
#include <hip/hip_bf16.h>

#define NTOK 2048
#define CDIM 256
#define HEADS 8
#define HD 32
// q scale: (1/sqrt(32)) * log2(e)  -> softmax exp becomes exp2
#define QSC 0.25505480068568306f

typedef __attribute__((ext_vector_type(8))) short short8;
typedef __attribute__((ext_vector_type(4))) float float4v;
typedef unsigned short ushort_t;
typedef unsigned int uint_t;
typedef __attribute__((ext_vector_type(4))) uint_t uint4v;

#define MFMA(a, b, c) __builtin_amdgcn_mfma_f32_16x16x32_bf16(a, b, c, 0, 0, 0)

__device__ __forceinline__ uint_t cvt_pk(float lo, float hi) {
    uint_t r;
    asm("v_cvt_pk_bf16_f32 %0, %1, %2" : "=v"(r) : "v"(lo), "v"(hi));
    return r;
}
__device__ __forceinline__ ushort_t f2bf(float f) {
    union { __hip_bfloat16 h; ushort_t u; } cv;
    cv.h = __float2bfloat16(f);   // RTNE
    return cv.u;
}
#if __has_builtin(__builtin_amdgcn_exp2f)
#define EXP2(x) __builtin_amdgcn_exp2f(x)
#else
#define EXP2(x) exp2f(x)
#endif

// Build a bf16x8 MFMA fragment from two QK^T accumulators (exp2 applied), via
// bit_cast (NO union punning -- R11's NaN suspect).
__device__ __forceinline__ short8 pack_p(float4v sA, float4v sB) {
    uint4v u;
    u[0] = cvt_pk(EXP2(sA[0]), EXP2(sA[1]));
    u[1] = cvt_pk(EXP2(sA[2]), EXP2(sA[3]));
    u[2] = cvt_pk(EXP2(sB[0]), EXP2(sB[1]));
    u[3] = cvt_pk(EXP2(sB[2]), EXP2(sB[3]));
    return __builtin_bit_cast(short8, u);
}

// ---------------- K0: all three f32 -> bf16 converts in one launch ----------------
// blocks [0,1024): x (262144 x8); [1024,1120): qkv_w (24576); [1120,1152): proj_w (8192)
__global__ __launch_bounds__(256) void cvt_all(const float* __restrict__ x,
                                               const float* __restrict__ w,
                                               const float* __restrict__ w2,
                                               uint4* __restrict__ xo,
                                               uint4* __restrict__ wo,
                                               uint4* __restrict__ w2o) {
    const int bid = blockIdx.x;
    const float* in; uint4* out; int i;
    if (bid < 1024)      { in = x;  out = xo;  i = bid * 256 + threadIdx.x; }
    else if (bid < 1120) { in = w;  out = wo;  i = (bid - 1024) * 256 + threadIdx.x; }
    else                 { in = w2; out = w2o; i = (bid - 1120) * 256 + threadIdx.x; }
    const float4* p = (const float4*)in + (size_t)2 * i;
    float4 a = p[0], bq = p[1];
    uint4 r;
    r.x = cvt_pk(a.x, a.y);   r.y = cvt_pk(a.z, a.w);
    r.z = cvt_pk(bq.x, bq.y); r.w = cvt_pk(bq.z, bq.w);
    out[i] = r;
}

// ---------------- K1: qkv bf16 MFMA GEMM, 32x64/wave, LDS-bounced epilogue ----------------
// C[d][n] = sum_c w[d][c] * x[b][n][c]. grid (12, 16, 4), block 256.
// 32-row d-tiles align with the 96-row head period -> wave is purely q, k, or v.
// V epilogue PERMUTES the key axis within each 32-token group: pi(m) =
// ((m&12)<<1)+(m&3)+((m&16)>>2), so the attention PV B-operand is exactly the
// QK^T C-layout and P never leaves registers in the attention kernel.
__global__ __launch_bounds__(256) void qkv_mfma(const ushort_t* __restrict__ x_bf,
                                                const ushort_t* __restrict__ w_bf,
                                                ushort_t* __restrict__ q_t,
                                                ushort_t* __restrict__ k_t,
                                                ushort_t* __restrict__ v_) {
    __shared__ ushort_t lds[4][2048];
    const int tid = threadIdx.x, wave = tid >> 6, lane = tid & 63;
    const int l15 = lane & 15, g = lane >> 4;
    const int b = blockIdx.z;
    const int dtile = blockIdx.x * 64 + (wave >> 1) * 32;
    const int ntile = blockIdx.y * 128 + (wave & 1) * 64;

    const ushort_t* A = w_bf + (size_t)dtile * CDIM + g * 8;
    const ushort_t* B = x_bf + ((size_t)b * NTOK + ntile) * CDIM + g * 8;

    float4v acc[2][4];
    #pragma unroll
    for (int i = 0; i < 2; ++i)
        #pragma unroll
        for (int j = 0; j < 4; ++j)
            #pragma unroll
            for (int r = 0; r < 4; ++r) acc[i][j][r] = 0.f;

    #pragma unroll
    for (int k0 = 0; k0 < CDIM; k0 += 32) {
        short8 af[2], bf[4];
        #pragma unroll
        for (int i = 0; i < 2; ++i)
            af[i] = *(const short8*)&A[(size_t)(l15 + 16 * i) * CDIM + k0];
        #pragma unroll
        for (int j = 0; j < 4; ++j)
            bf[j] = *(const short8*)&B[(size_t)(l15 + 16 * j) * CDIM + k0];
        #pragma unroll
        for (int i = 0; i < 2; ++i)
            #pragma unroll
            for (int j = 0; j < 4; ++j)
                acc[i][j] = MFMA(af[i], bf[j], acc[i][j]);
    }

    const int hq = (dtile * 683) >> 16;     // dtile/96 (wave-uniform)
    const int tl = dtile - hq * 96;         // 0 (=q), 32 (=k), 64 (=v)
    const size_t bh = (size_t)(b * HEADS + hq);
    ushort_t* W = lds[wave];

    if (tl == 64) {
        // --- v[bh][dloc][n] n-fast, key-permuted within each 32-group.
        #pragma unroll
        for (int i = 0; i < 2; ++i)
            #pragma unroll
            for (int j = 0; j < 4; ++j) {
                const int m = (j & 1) * 16 + l15;                      // logical 0..31
                const int p = ((m & 12) << 1) + (m & 3) + ((m & 16) >> 2);
                const int phys = (j >> 1) * 32 + p;                    // 0..63
                const int c = phys >> 3;
                #pragma unroll
                for (int r = 0; r < 4; ++r) {
                    const int d = i * 16 + g * 4 + r;
                    W[d * 64 + ((c ^ (d & 7)) * 8) + (phys & 7)] = f2bf(acc[i][j][r]);
                }
            }
        ushort_t* vb = v_ + bh * ((size_t)NTOK * HD);
        #pragma unroll
        for (int t = 0; t < 4; ++t) {
            const int d = t * 8 + (lane >> 3), c = lane & 7;
            uint4 val = *(const uint4*)&W[d * 64 + ((c ^ (d & 7)) * 8)];
            *(uint4*)&vb[(size_t)d * NTOK + ntile + c * 8] = val;
        }
    } else {
        // --- q_t / k_t [bh][n][dloc] d-fast.  LDS tile [64 n][32 d], 16B-chunk XOR swizzle.
        ushort_t* base = (tl ? k_t : q_t) + bh * ((size_t)NTOK * HD);
        const float mul = tl ? 1.f : QSC;
        #pragma unroll
        for (int i = 0; i < 2; ++i)
            #pragma unroll
            for (int j = 0; j < 4; ++j) {
                uint2 pk;
                pk.x = cvt_pk(acc[i][j][0] * mul, acc[i][j][1] * mul);
                pk.y = cvt_pk(acc[i][j][2] * mul, acc[i][j][3] * mul);
                const int row = j * 16 + l15;            // n-local 0..63
                const int c16 = i * 2 + (g >> 1);        // 8-elem chunk 0..3
                *(uint2*)&W[row * 32 + ((c16 ^ (row & 3)) * 8) + (g & 1) * 4] = pk;
            }
        #pragma unroll
        for (int t = 0; t < 4; ++t) {
            const int row = t * 16 + (lane >> 2), c = lane & 3;
            uint4 val = *(const uint4*)&W[row * 32 + ((c ^ (row & 3)) * 8)];
            *(uint4*)&base[(size_t)(ntile + row) * HD + c * 8] = val;
        }
    }
}

// ---------------- K2: MFMA flash attention, P fully in-register ----------------
// Block 256 = 4 waves: wave>>1 = query subtile (32 q), wave&1 = key half (1024 keys).
// grid (BH=32, 2048/64) -- bh on x so bh == XCD (mod 8): K/V stay L2-local.
// V's key axis is pre-permuted by qkv_mfma: B-frag element e of lane (l15,g) is
// logical key kappa(g,e) = {g*4+e | e<4 ; 16+g*4+(e-4) | e>=4}, and physical V
// column g*8+e holds exactly that logical key. No main-loop LDS at all.
__global__ __launch_bounds__(256) void attn_mfma(const ushort_t* __restrict__ q_t,
                                                 const ushort_t* __restrict__ k_t,
                                                 const ushort_t* __restrict__ v_,
                                                 ushort_t* __restrict__ preT) {
    __shared__ float smem[4][1152];    // combine buffer only (64 lanes x 18 f32 per wave)
    const int tid = threadIdx.x, wave = tid >> 6, lane = tid & 63;
    const int l15 = lane & 15, g = lane >> 4;
    const int bh = blockIdx.x, b = bh >> 3, h = bh & 7;
    const int j0 = blockIdx.y * 64 + (wave >> 1) * 32;
    const int khalf = wave & 1;

    const ushort_t* qb = q_t + (size_t)bh * (NTOK * HD);
    const ushort_t* kb = k_t + (size_t)bh * (NTOK * HD);
    const ushort_t* vb = v_  + (size_t)bh * (NTOK * HD);

    short8 qf0 = *(const short8*)&qb[(size_t)(j0 + l15) * HD + g * 8];
    short8 qf1 = *(const short8*)&qb[(size_t)(j0 + 16 + l15) * HD + g * 8];

    short8 ones;
    #pragma unroll
    for (int r = 0; r < 8; ++r) ones[r] = (short)0x3F80;   // bf16 1.0

    const float4v z4 = {0.f, 0.f, 0.f, 0.f};
    float4v o00 = z4, o01 = z4, o10 = z4, o11 = z4;   // unnormalized O
    float4v lacc0 = z4, lacc1 = z4;                   // column sums of P via MFMA(ones,P)

    const int kbeg = khalf * 1024, kend = kbeg + 1024;
    short8 aK0 = *(const short8*)&kb[(size_t)(kbeg + l15) * HD + g * 8];
    short8 aK1 = *(const short8*)&kb[(size_t)(kbeg + 16 + l15) * HD + g * 8];
    short8 aV0 = *(const short8*)&vb[(size_t)l15 * NTOK + kbeg + g * 8];
    short8 aV1 = *(const short8*)&vb[(size_t)(16 + l15) * NTOK + kbeg + g * 8];

    for (int i0 = kbeg; i0 < kend; i0 += 32) {
        const int ip = (i0 + 32 < kend) ? i0 + 32 : kbeg;   // prefetch (wrap = safe addr)
        short8 nK0 = *(const short8*)&kb[(size_t)(ip + l15) * HD + g * 8];
        short8 nK1 = *(const short8*)&kb[(size_t)(ip + 16 + l15) * HD + g * 8];
        short8 nV0 = *(const short8*)&vb[(size_t)l15 * NTOK + ip + g * 8];
        short8 nV1 = *(const short8*)&vb[(size_t)(16 + l15) * NTOK + ip + g * 8];

        float4v s00 = MFMA(aK0, qf0, z4);
        float4v s10 = MFMA(aK1, qf0, z4);
        float4v s01 = MFMA(aK0, qf1, z4);
        float4v s11 = MFMA(aK1, qf1, z4);

        short8 p0 = pack_p(s00, s10);
        short8 p1 = pack_p(s01, s11);

        lacc0 = MFMA(ones, p0, lacc0);
        lacc1 = MFMA(ones, p1, lacc1);
        o00 = MFMA(aV0, p0, o00);
        o01 = MFMA(aV0, p1, o01);
        o10 = MFMA(aV1, p0, o10);
        o11 = MFMA(aV1, p1, o11);

        aK0 = nK0; aK1 = nK1; aV0 = nV0; aV1 = nV1;
    }

    // cross-wave combine (key halves)
    float* dst = &smem[wave][lane * 18];
    #pragma unroll
    for (int r = 0; r < 4; ++r) {
        dst[r] = o00[r]; dst[4 + r] = o01[r]; dst[8 + r] = o10[r]; dst[12 + r] = o11[r];
    }
    dst[16] = lacc0[0]; dst[17] = lacc1[0];
    __syncthreads();

    if (khalf == 0) {
        const float* cp = &smem[wave ^ 1][lane * 18];
        #pragma unroll
        for (int r = 0; r < 4; ++r) {
            o00[r] += cp[r]; o01[r] += cp[4 + r]; o10[r] += cp[8 + r]; o11[r] += cp[12 + r];
        }
        const float rl0 = 1.f / (lacc0[0] + cp[16]);
        const float rl1 = 1.f / (lacc1[0] + cp[17]);

        ushort_t* pb_ = preT + ((size_t)b * NTOK + j0) * CDIM + h * HD;
        uint2 w0, w1, w2, w3;
        w0.x = cvt_pk(o00[0] * rl0, o00[1] * rl0); w0.y = cvt_pk(o00[2] * rl0, o00[3] * rl0);
        w1.x = cvt_pk(o01[0] * rl1, o01[1] * rl1); w1.y = cvt_pk(o01[2] * rl1, o01[3] * rl1);
        w2.x = cvt_pk(o10[0] * rl0, o10[1] * rl0); w2.y = cvt_pk(o10[2] * rl0, o10[3] * rl0);
        w3.x = cvt_pk(o11[0] * rl1, o11[1] * rl1); w3.y = cvt_pk(o11[2] * rl1, o11[3] * rl1);
        *(uint2*)&pb_[(size_t)l15 * CDIM + g * 4] = w0;
        *(uint2*)&pb_[(size_t)(16 + l15) * CDIM + g * 4] = w1;
        *(uint2*)&pb_[(size_t)l15 * CDIM + 16 + g * 4] = w2;
        *(uint2*)&pb_[(size_t)(16 + l15) * CDIM + 16 + g * 4] = w3;
    }
}

// ---------------- K3: proj bf16 MFMA GEMM + bias, 32x32/wave ----------------
// out[b][dd][n] = sum_c w2[dd][c] * preT[b][n][c] + pb[dd].  grid (4, 32, 4).
__global__ __launch_bounds__(256) void proj_mfma(const ushort_t* __restrict__ preT,
                                                 const ushort_t* __restrict__ w2_bf,
                                                 const float* __restrict__ pb,
                                                 float* __restrict__ out) {
    const int tid = threadIdx.x, wave = tid >> 6, lane = tid & 63;
    const int l15 = lane & 15, g = lane >> 4;
    const int b = blockIdx.z;
    const int dtile = blockIdx.x * 64 + (wave >> 1) * 32;
    const int ntile = blockIdx.y * 64 + (wave & 1) * 32;

    const ushort_t* A = w2_bf + (size_t)dtile * CDIM + g * 8;
    const ushort_t* B = preT + ((size_t)b * NTOK + ntile) * CDIM + g * 8;

    float4v acc[2][2];
    #pragma unroll
    for (int i = 0; i < 2; ++i)
        #pragma unroll
        for (int j = 0; j < 2; ++j)
            #pragma unroll
            for (int r = 0; r < 4; ++r) acc[i][j][r] = 0.f;

    #pragma unroll
    for (int k0 = 0; k0 < CDIM; k0 += 32) {
        short8 af[2], bf[2];
        #pragma unroll
        for (int i = 0; i < 2; ++i)
            af[i] = *(const short8*)&A[(size_t)(l15 + 16 * i) * CDIM + k0];
        #pragma unroll
        for (int j = 0; j < 2; ++j)
            bf[j] = *(const short8*)&B[(size_t)(l15 + 16 * j) * CDIM + k0];
        #pragma unroll
        for (int i = 0; i < 2; ++i)
            #pragma unroll
            for (int j = 0; j < 2; ++j)
                acc[i][j] = MFMA(af[i], bf[j], acc[i][j]);
    }

    #pragma unroll
    for (int i = 0; i < 2; ++i) {
        #pragma unroll
        for (int r = 0; r < 4; ++r) {
            const int d = dtile + i * 16 + g * 4 + r;
            const float bias = pb[d];
            float* orow = out + ((size_t)b * CDIM + d) * NTOK + ntile;
            #pragma unroll
            for (int j = 0; j < 2; ++j)
                orow[j * 16 + l15] = acc[i][j][r] + bias;
        }
    }
}

extern "C" void kernel_launch(void* const* d_in, const int* in_sizes, int n_in,
                              void* d_out, int out_size, void* d_ws, size_t ws_size,
                              hipStream_t stream) {
    const float* x      = (const float*)d_in[0];   // [4,2048,256]
    const float* qkv_w  = (const float*)d_in[1];   // [768,256]
    const float* proj_w = (const float*)d_in[2];   // [256,256]
    const float* proj_b = (const float*)d_in[3];   // [256]
    float* out = (float*)d_out;                    // [4,256,2048]

    // ws: x_bf/preT alias 0-4MB | w_bf 4MB | w2_bf 4.5MB | q_t 5MB | k_t 9MB | v 13MB (17MB)
    char* ws = (char*)d_ws;
    ushort_t* x_bf  = (ushort_t*)(ws);
    ushort_t* preT  = (ushort_t*)(ws);                  // alias: x_bf dead after qkv
    ushort_t* w_bf  = (ushort_t*)(ws + (size_t)4 * 1024 * 1024);
    ushort_t* w2_bf = (ushort_t*)(ws + (size_t)4608 * 1024);
    ushort_t* q_t   = (ushort_t*)(ws + (size_t)5 * 1024 * 1024);
    ushort_t* k_t   = (ushort_t*)(ws + (size_t)9 * 1024 * 1024);
    ushort_t* v_    = (ushort_t*)(ws + (size_t)13 * 1024 * 1024);

    cvt_all<<<1152, 256, 0, stream>>>(x, qkv_w, proj_w,
                                      (uint4*)x_bf, (uint4*)w_bf, (uint4*)w2_bf);
    qkv_mfma<<<dim3(12, 16, 4), 256, 0, stream>>>(x_bf, w_bf, q_t, k_t, v_);
    attn_mfma<<<dim3(4 * HEADS, NTOK / 64), 256, 0, stream>>>(q_t, k_t, v_, preT);
    proj_mfma<<<dim3(4, 32, 4), 256, 0, stream>>>(preT, w2_bf, proj_b, out);
}

// Round 15
// 143.378 us; speedup vs baseline: 1.4728x; 1.0066x over previous
//
#include <hip/hip_runtime.h>
#include <hip/hip_bf16.h>

#define NTOK 2048
#define CDIM 256
#define HEADS 8
#define HD 32
// q scale: (1/sqrt(32)) * log2(e)  -> softmax exp becomes exp2
#define QSC 0.25505480068568306f

typedef __attribute__((ext_vector_type(8))) short short8;
typedef __attribute__((ext_vector_type(4))) float float4v;
typedef unsigned short ushort_t;
typedef unsigned int uint_t;
typedef __attribute__((ext_vector_type(4))) uint_t uint4v;

#define MFMA(a, b, c) __builtin_amdgcn_mfma_f32_16x16x32_bf16(a, b, c, 0, 0, 0)

__device__ __forceinline__ uint_t cvt_pk(float lo, float hi) {
    uint_t r;
    asm("v_cvt_pk_bf16_f32 %0, %1, %2" : "=v"(r) : "v"(lo), "v"(hi));
    return r;
}
__device__ __forceinline__ ushort_t f2bf(float f) {
    union { __hip_bfloat16 h; ushort_t u; } cv;
    cv.h = __float2bfloat16(f);   // RTNE
    return cv.u;
}
#if __has_builtin(__builtin_amdgcn_exp2f)
#define EXP2(x) __builtin_amdgcn_exp2f(x)
#else
#define EXP2(x) exp2f(x)
#endif

// Build a bf16x8 MFMA fragment from two QK^T accumulators (exp2 applied), via
// bit_cast (proven R13; NOT the R11 union pun).
__device__ __forceinline__ short8 pack_p(float4v sA, float4v sB) {
    uint4v u;
    u[0] = cvt_pk(EXP2(sA[0]), EXP2(sA[1]));
    u[1] = cvt_pk(EXP2(sA[2]), EXP2(sA[3]));
    u[2] = cvt_pk(EXP2(sB[0]), EXP2(sB[1]));
    u[3] = cvt_pk(EXP2(sB[2]), EXP2(sB[3]));
    return __builtin_bit_cast(short8, u);
}

// ---------------- K0: all three f32 -> bf16 converts in one launch ----------------
// blocks [0,1024): x (262144 x8); [1024,1120): qkv_w (24576); [1120,1152): proj_w (8192)
__global__ __launch_bounds__(256) void cvt_all(const float* __restrict__ x,
                                               const float* __restrict__ w,
                                               const float* __restrict__ w2,
                                               uint4* __restrict__ xo,
                                               uint4* __restrict__ wo,
                                               uint4* __restrict__ w2o) {
    const int bid = blockIdx.x;
    const float* in; uint4* out; int i;
    if (bid < 1024)      { in = x;  out = xo;  i = bid * 256 + threadIdx.x; }
    else if (bid < 1120) { in = w;  out = wo;  i = (bid - 1024) * 256 + threadIdx.x; }
    else                 { in = w2; out = w2o; i = (bid - 1120) * 256 + threadIdx.x; }
    const float4* p = (const float4*)in + (size_t)2 * i;
    float4 a = p[0], bq = p[1];
    uint4 r;
    r.x = cvt_pk(a.x, a.y);   r.y = cvt_pk(a.z, a.w);
    r.z = cvt_pk(bq.x, bq.y); r.w = cvt_pk(bq.z, bq.w);
    out[i] = r;
}

// ---------------- K1: qkv bf16 MFMA GEMM, 32x64/wave, LDS-bounced epilogue ----------------
// C[d][n] = sum_c w[d][c] * x[b][n][c]. grid (12, 16, 4), block 256.
// V epilogue PERMUTES the key axis within each 32-token group: pi(m) =
// ((m&12)<<1)+(m&3)+((m&16)>>2), so the attention PV B-operand is exactly the
// QK^T C-layout and P never leaves registers in the attention kernel.
__global__ __launch_bounds__(256) void qkv_mfma(const ushort_t* __restrict__ x_bf,
                                                const ushort_t* __restrict__ w_bf,
                                                ushort_t* __restrict__ q_t,
                                                ushort_t* __restrict__ k_t,
                                                ushort_t* __restrict__ v_) {
    __shared__ ushort_t lds[4][2048];
    const int tid = threadIdx.x, wave = tid >> 6, lane = tid & 63;
    const int l15 = lane & 15, g = lane >> 4;
    const int b = blockIdx.z;
    const int dtile = blockIdx.x * 64 + (wave >> 1) * 32;
    const int ntile = blockIdx.y * 128 + (wave & 1) * 64;

    const ushort_t* A = w_bf + (size_t)dtile * CDIM + g * 8;
    const ushort_t* B = x_bf + ((size_t)b * NTOK + ntile) * CDIM + g * 8;

    float4v acc[2][4];
    #pragma unroll
    for (int i = 0; i < 2; ++i)
        #pragma unroll
        for (int j = 0; j < 4; ++j)
            #pragma unroll
            for (int r = 0; r < 4; ++r) acc[i][j][r] = 0.f;

    #pragma unroll
    for (int k0 = 0; k0 < CDIM; k0 += 32) {
        short8 af[2], bf[4];
        #pragma unroll
        for (int i = 0; i < 2; ++i)
            af[i] = *(const short8*)&A[(size_t)(l15 + 16 * i) * CDIM + k0];
        #pragma unroll
        for (int j = 0; j < 4; ++j)
            bf[j] = *(const short8*)&B[(size_t)(l15 + 16 * j) * CDIM + k0];
        #pragma unroll
        for (int i = 0; i < 2; ++i)
            #pragma unroll
            for (int j = 0; j < 4; ++j)
                acc[i][j] = MFMA(af[i], bf[j], acc[i][j]);
    }

    const int hq = (dtile * 683) >> 16;     // dtile/96 (wave-uniform)
    const int tl = dtile - hq * 96;         // 0 (=q), 32 (=k), 64 (=v)
    const size_t bh = (size_t)(b * HEADS + hq);
    ushort_t* W = lds[wave];

    if (tl == 64) {
        // --- v[bh][dloc][n] n-fast, key-permuted within each 32-group.
        #pragma unroll
        for (int i = 0; i < 2; ++i)
            #pragma unroll
            for (int j = 0; j < 4; ++j) {
                const int m = (j & 1) * 16 + l15;                      // logical 0..31
                const int p = ((m & 12) << 1) + (m & 3) + ((m & 16) >> 2);
                const int phys = (j >> 1) * 32 + p;                    // 0..63
                const int c = phys >> 3;
                #pragma unroll
                for (int r = 0; r < 4; ++r) {
                    const int d = i * 16 + g * 4 + r;
                    W[d * 64 + ((c ^ (d & 7)) * 8) + (phys & 7)] = f2bf(acc[i][j][r]);
                }
            }
        ushort_t* vb = v_ + bh * ((size_t)NTOK * HD);
        #pragma unroll
        for (int t = 0; t < 4; ++t) {
            const int d = t * 8 + (lane >> 3), c = lane & 7;
            uint4 val = *(const uint4*)&W[d * 64 + ((c ^ (d & 7)) * 8)];
            *(uint4*)&vb[(size_t)d * NTOK + ntile + c * 8] = val;
        }
    } else {
        // --- q_t / k_t [bh][n][dloc] d-fast.  LDS tile [64 n][32 d], 16B-chunk XOR swizzle.
        ushort_t* base = (tl ? k_t : q_t) + bh * ((size_t)NTOK * HD);
        const float mul = tl ? 1.f : QSC;
        #pragma unroll
        for (int i = 0; i < 2; ++i)
            #pragma unroll
            for (int j = 0; j < 4; ++j) {
                uint2 pk;
                pk.x = cvt_pk(acc[i][j][0] * mul, acc[i][j][1] * mul);
                pk.y = cvt_pk(acc[i][j][2] * mul, acc[i][j][3] * mul);
                const int row = j * 16 + l15;            // n-local 0..63
                const int c16 = i * 2 + (g >> 1);        // 8-elem chunk 0..3
                *(uint2*)&W[row * 32 + ((c16 ^ (row & 3)) * 8) + (g & 1) * 4] = pk;
            }
        #pragma unroll
        for (int t = 0; t < 4; ++t) {
            const int row = t * 16 + (lane >> 2), c = lane & 3;
            uint4 val = *(const uint4*)&W[row * 32 + ((c ^ (row & 3)) * 8)];
            *(uint4*)&base[(size_t)(ntile + row) * HD + c * 8] = val;
        }
    }
}

// ---------------- K2: MFMA flash attention, key-split x4, 8 waves/SIMD ----------------
// Block 256 = 4 waves: ALL waves share one 32-query tile; wave = key quarter
// (512 keys each, 16 iterations). grid (BH=32, 2048/32=64) = 2048 blocks ->
// 8 blocks/CU, 8 waves/SIMD (TLP hides L2 latency). bh on x: K/V L2-local.
// V pre-permuted by qkv_mfma -> P stays in registers; no main-loop LDS.
__global__ __launch_bounds__(256) void attn_mfma(const ushort_t* __restrict__ q_t,
                                                 const ushort_t* __restrict__ k_t,
                                                 const ushort_t* __restrict__ v_,
                                                 ushort_t* __restrict__ preT) {
    __shared__ float smem[4][1152];    // combine buffer (64 lanes x 18 f32 per wave)
    const int tid = threadIdx.x, wave = tid >> 6, lane = tid & 63;
    const int l15 = lane & 15, g = lane >> 4;
    const int bh = blockIdx.x, b = bh >> 3, h = bh & 7;
    const int j0 = blockIdx.y * 32;

    const ushort_t* qb = q_t + (size_t)bh * (NTOK * HD);
    const ushort_t* kb = k_t + (size_t)bh * (NTOK * HD);
    const ushort_t* vb = v_  + (size_t)bh * (NTOK * HD);

    short8 qf0 = *(const short8*)&qb[(size_t)(j0 + l15) * HD + g * 8];
    short8 qf1 = *(const short8*)&qb[(size_t)(j0 + 16 + l15) * HD + g * 8];

    short8 ones;
    #pragma unroll
    for (int r = 0; r < 8; ++r) ones[r] = (short)0x3F80;   // bf16 1.0

    const float4v z4 = {0.f, 0.f, 0.f, 0.f};
    float4v o00 = z4, o01 = z4, o10 = z4, o11 = z4;   // unnormalized O
    float4v lacc0 = z4, lacc1 = z4;                   // column sums of P via MFMA(ones,P)

    const int kbeg = wave * 512, kend = kbeg + 512;
    short8 aK0 = *(const short8*)&kb[(size_t)(kbeg + l15) * HD + g * 8];
    short8 aK1 = *(const short8*)&kb[(size_t)(kbeg + 16 + l15) * HD + g * 8];
    short8 aV0 = *(const short8*)&vb[(size_t)l15 * NTOK + kbeg + g * 8];
    short8 aV1 = *(const short8*)&vb[(size_t)(16 + l15) * NTOK + kbeg + g * 8];

    for (int i0 = kbeg; i0 < kend; i0 += 32) {
        const int ip = (i0 + 32 < kend) ? i0 + 32 : kbeg;   // prefetch (wrap = safe addr)
        short8 nK0 = *(const short8*)&kb[(size_t)(ip + l15) * HD + g * 8];
        short8 nK1 = *(const short8*)&kb[(size_t)(ip + 16 + l15) * HD + g * 8];
        short8 nV0 = *(const short8*)&vb[(size_t)l15 * NTOK + ip + g * 8];
        short8 nV1 = *(const short8*)&vb[(size_t)(16 + l15) * NTOK + ip + g * 8];

        float4v s00 = MFMA(aK0, qf0, z4);
        float4v s10 = MFMA(aK1, qf0, z4);
        float4v s01 = MFMA(aK0, qf1, z4);
        float4v s11 = MFMA(aK1, qf1, z4);

        short8 p0 = pack_p(s00, s10);
        short8 p1 = pack_p(s01, s11);

        lacc0 = MFMA(ones, p0, lacc0);
        lacc1 = MFMA(ones, p1, lacc1);
        o00 = MFMA(aV0, p0, o00);
        o01 = MFMA(aV0, p1, o01);
        o10 = MFMA(aV1, p0, o10);
        o11 = MFMA(aV1, p1, o11);

        aK0 = nK0; aK1 = nK1; aV0 = nV0; aV1 = nV1;
    }

    // 4-way cross-wave combine (key quarters)
    float* dst = &smem[wave][lane * 18];
    #pragma unroll
    for (int r = 0; r < 4; ++r) {
        dst[r] = o00[r]; dst[4 + r] = o01[r]; dst[8 + r] = o10[r]; dst[12 + r] = o11[r];
    }
    dst[16] = lacc0[0]; dst[17] = lacc1[0];
    __syncthreads();

    if (wave == 0) {
        float ls0 = lacc0[0], ls1 = lacc1[0];
        #pragma unroll
        for (int wq = 1; wq < 4; ++wq) {
            const float* cp = &smem[wq][lane * 18];
            #pragma unroll
            for (int r = 0; r < 4; ++r) {
                o00[r] += cp[r]; o01[r] += cp[4 + r];
                o10[r] += cp[8 + r]; o11[r] += cp[12 + r];
            }
            ls0 += cp[16]; ls1 += cp[17];
        }
        const float rl0 = 1.f / ls0;
        const float rl1 = 1.f / ls1;

        ushort_t* pb_ = preT + ((size_t)b * NTOK + j0) * CDIM + h * HD;
        uint2 w0, w1, w2, w3;
        w0.x = cvt_pk(o00[0] * rl0, o00[1] * rl0); w0.y = cvt_pk(o00[2] * rl0, o00[3] * rl0);
        w1.x = cvt_pk(o01[0] * rl1, o01[1] * rl1); w1.y = cvt_pk(o01[2] * rl1, o01[3] * rl1);
        w2.x = cvt_pk(o10[0] * rl0, o10[1] * rl0); w2.y = cvt_pk(o10[2] * rl0, o10[3] * rl0);
        w3.x = cvt_pk(o11[0] * rl1, o11[1] * rl1); w3.y = cvt_pk(o11[2] * rl1, o11[3] * rl1);
        *(uint2*)&pb_[(size_t)l15 * CDIM + g * 4] = w0;
        *(uint2*)&pb_[(size_t)(16 + l15) * CDIM + g * 4] = w1;
        *(uint2*)&pb_[(size_t)l15 * CDIM + 16 + g * 4] = w2;
        *(uint2*)&pb_[(size_t)(16 + l15) * CDIM + 16 + g * 4] = w3;
    }
}

// ---------------- K3: proj bf16 MFMA GEMM + bias, 32x32/wave ----------------
// out[b][dd][n] = sum_c w2[dd][c] * preT[b][n][c] + pb[dd].  grid (4, 32, 4).
__global__ __launch_bounds__(256) void proj_mfma(const ushort_t* __restrict__ preT,
                                                 const ushort_t* __restrict__ w2_bf,
                                                 const float* __restrict__ pb,
                                                 float* __restrict__ out) {
    const int tid = threadIdx.x, wave = tid >> 6, lane = tid & 63;
    const int l15 = lane & 15, g = lane >> 4;
    const int b = blockIdx.z;
    const int dtile = blockIdx.x * 64 + (wave >> 1) * 32;
    const int ntile = blockIdx.y * 64 + (wave & 1) * 32;

    const ushort_t* A = w2_bf + (size_t)dtile * CDIM + g * 8;
    const ushort_t* B = preT + ((size_t)b * NTOK + ntile) * CDIM + g * 8;

    float4v acc[2][2];
    #pragma unroll
    for (int i = 0; i < 2; ++i)
        #pragma unroll
        for (int j = 0; j < 2; ++j)
            #pragma unroll
            for (int r = 0; r < 4; ++r) acc[i][j][r] = 0.f;

    #pragma unroll
    for (int k0 = 0; k0 < CDIM; k0 += 32) {
        short8 af[2], bf[2];
        #pragma unroll
        for (int i = 0; i < 2; ++i)
            af[i] = *(const short8*)&A[(size_t)(l15 + 16 * i) * CDIM + k0];
        #pragma unroll
        for (int j = 0; j < 2; ++j)
            bf[j] = *(const short8*)&B[(size_t)(l15 + 16 * j) * CDIM + k0];
        #pragma unroll
        for (int i = 0; i < 2; ++i)
            #pragma unroll
            for (int j = 0; j < 2; ++j)
                acc[i][j] = MFMA(af[i], bf[j], acc[i][j]);
    }

    #pragma unroll
    for (int i = 0; i < 2; ++i) {
        #pragma unroll
        for (int r = 0; r < 4; ++r) {
            const int d = dtile + i * 16 + g * 4 + r;
            const float bias = pb[d];
            float* orow = out + ((size_t)b * CDIM + d) * NTOK + ntile;
            #pragma unroll
            for (int j = 0; j < 2; ++j)
                orow[j * 16 + l15] = acc[i][j][r] + bias;
        }
    }
}

extern "C" void kernel_launch(void* const* d_in, const int* in_sizes, int n_in,
                              void* d_out, int out_size, void* d_ws, size_t ws_size,
                              hipStream_t stream) {
    const float* x      = (const float*)d_in[0];   // [4,2048,256]
    const float* qkv_w  = (const float*)d_in[1];   // [768,256]
    const float* proj_w = (const float*)d_in[2];   // [256,256]
    const float* proj_b = (const float*)d_in[3];   // [256]
    float* out = (float*)d_out;                    // [4,256,2048]

    // ws: x_bf/preT alias 0-4MB | w_bf 4MB | w2_bf 4.5MB | q_t 5MB | k_t 9MB | v 13MB (17MB)
    char* ws = (char*)d_ws;
    ushort_t* x_bf  = (ushort_t*)(ws);
    ushort_t* preT  = (ushort_t*)(ws);                  // alias: x_bf dead after qkv
    ushort_t* w_bf  = (ushort_t*)(ws + (size_t)4 * 1024 * 1024);
    ushort_t* w2_bf = (ushort_t*)(ws + (size_t)4608 * 1024);
    ushort_t* q_t   = (ushort_t*)(ws + (size_t)5 * 1024 * 1024);
    ushort_t* k_t   = (ushort_t*)(ws + (size_t)9 * 1024 * 1024);
    ushort_t* v_    = (ushort_t*)(ws + (size_t)13 * 1024 * 1024);

    cvt_all<<<1152, 256, 0, stream>>>(x, qkv_w, proj_w,
                                      (uint4*)x_bf, (uint4*)w_bf, (uint4*)w2_bf);
    qkv_mfma<<<dim3(12, 16, 4), 256, 0, stream>>>(x_bf, w_bf, q_t, k_t, v_);
    attn_mfma<<<dim3(4 * HEADS, NTOK / 32), 256, 0, stream>>>(q_t, k_t, v_, preT);
    proj_mfma<<<dim3(4, 32, 4), 256, 0, stream>>>(preT, w2_bf, proj_b, out);
}